// Round 9
// baseline (3935.873 us; speedup 1.0000x reference)
//
#include <hip/hip_runtime.h>

#define BB 16
#define NN 2048
#define NITERS 100

// k = log2(e)/eps, eps = 0.05
#define K2E      28.853900817779268f
#define TWO_K2E  57.707801635558536f
#define INV_K2E  0.034657359027997264f
#define INV4K    0.008664339756999316f   // 1/(4k)
#define LMU      (-11.0f)                // log2(1/2048)

#if __has_builtin(__builtin_amdgcn_exp2f)
#define EXP2F(x) __builtin_amdgcn_exp2f(x)
#else
#define EXP2F(x) exp2f(x)
#endif

// Sum-pass: 4 register-resident row points vs ALL 2048 cols of AoS table
// (2k*c0,2k*c1,2k*c2,dual). Full 64-lane reduction; lanes 0..3 return the
// 4 row sums (row = ((lane&1)<<1)|((lane>>1)&1)).
__device__ __forceinline__ float sumpass4(
    const float4* __restrict__ tab,
    const float* xr0, const float* xr1, const float* xr2, int lane)
{
    float acc[4] = {0.f, 0.f, 0.f, 0.f};
    #pragma unroll 2
    for (int s = 0; s < 32; ++s) {
        const float4 t = tab[(s << 6) + lane];
        #pragma unroll
        for (int k = 0; k < 4; ++k)
            acc[k] += EXP2F(fmaf(xr0[k], t.x, fmaf(xr1[k], t.y, fmaf(xr2[k], t.z, t.w))));
    }
    const bool b0 = lane & 1, b1 = lane & 2;
    float v2[2], v1;
    #pragma unroll
    for (int i = 0; i < 2; ++i) {
        float recv = __shfl_xor(b0 ? acc[i] : acc[i + 2], 1, 64);
        v2[i] = (b0 ? acc[i + 2] : acc[i]) + recv;
    }
    {
        float recv = __shfl_xor(b1 ? v2[0] : v2[1], 2, 64);
        v1 = (b1 ? v2[1] : v2[0]) + recv;
    }
    v1 += __shfl_xor(v1, 4, 64);
    v1 += __shfl_xor(v1, 8, 64);
    v1 += __shfl_xor(v1, 16, 64);
    v1 += __shfl_xor(v1, 32, 64);
    return v1;
}

// Epilogue partial: sum_j P_ij*C_ij over 4 rows x all j. A_i from tX.w.
__device__ __forceinline__ float epil4(
    const float4* __restrict__ tY, const float4* __restrict__ tX,
    const float* xr0, const float* xr1, const float* xr2,
    int rloc, int lane)
{
    float Ak[4], x2k[4];
    #pragma unroll
    for (int k = 0; k < 4; ++k) {
        Ak[k]  = tX[rloc + k].w;                       // broadcast LDS read
        x2k[k] = K2E * (xr0[k]*xr0[k] + xr1[k]*xr1[k] + xr2[k]*xr2[k]);
    }
    float acc = 0.f;
    for (int s = 0; s < 32; ++s) {
        const float4 t = tY[(s << 6) + lane];
        const float q = (t.x*t.x + t.y*t.y + t.z*t.z) * INV4K;   // k|y|^2
        #pragma unroll
        for (int k = 0; k < 4; ++k) {
            float d = fmaf(xr0[k], t.x, fmaf(xr1[k], t.y, fmaf(xr2[k], t.z, t.w)));
            float P = EXP2F(d + Ak[k]);                          // exp(logP)
            float C = fmaxf((x2k[k] + q - (d - t.w)) * INV_K2E, 0.f);
            acc = fmaf(P, C, acc);
        }
    }
    return acc;
}

// grid: 256 blocks x 1024 threads (1 block/CU, co-op). pair = blk&7 (XCD-
// local), q = blk>>3 owns 64 rows of both batches (2p, 2p+1). Deterministic
// software pipeline (R8-verified schedule): every wait has one full compute
// phase between the matching posts and the wait.
__global__ __launch_bounds__(1024) void emd_sinkhorn(
    const float* __restrict__ x, const float* __restrict__ y,
    float* __restrict__ Af, float* __restrict__ Bf,
    int* __restrict__ cntb, float* __restrict__ out)
{
    extern __shared__ float4 T[];    // 4*NN float4 = 128 KB
    __shared__ float wsum[16];

    float4* tX0 = T;                 // (2k*x, A) batch0
    float4* tY0 = T + NN;            // (2k*y, B) batch0
    float4* tX1 = T + 2 * NN;
    float4* tY1 = T + 3 * NN;

    const int tid  = threadIdx.x;
    const int lane = tid & 63;
    const int w    = tid >> 6;        // 0..15
    const int blk  = blockIdx.x;
    const int pair = blk & 7;
    const int q    = blk >> 3;        // 0..31
    const int b0   = pair * 2, b1 = b0 + 1;
    const int base0 = b0 * NN, base1 = b1 * NN;
    const int rloc  = q * 64 + w * 4;       // my wave's 4 rows (per batch)
    int* c0 = cntb + b0 * 64;
    int* c1 = cntb + b1 * 64;

    // ---- prologue: stage AoS tables; tY.w = B0 = -k|y|^2 ----
    #pragma unroll
    for (int v = 0; v < 2; ++v) {
        const int p = tid + (v << 10);
        {
            const float* px = x + 3 * (size_t)(base0 + p);
            tX0[p] = make_float4(TWO_K2E*px[0], TWO_K2E*px[1], TWO_K2E*px[2], 0.f);
            const float* py = y + 3 * (size_t)(base0 + p);
            const float a = py[0], b = py[1], c = py[2];
            tY0[p] = make_float4(TWO_K2E*a, TWO_K2E*b, TWO_K2E*c,
                                 -K2E * (a*a + b*b + c*c));
        }
        {
            const float* px = x + 3 * (size_t)(base1 + p);
            tX1[p] = make_float4(TWO_K2E*px[0], TWO_K2E*px[1], TWO_K2E*px[2], 0.f);
            const float* py = y + 3 * (size_t)(base1 + p);
            const float a = py[0], b = py[1], c = py[2];
            tY1[p] = make_float4(TWO_K2E*a, TWO_K2E*b, TWO_K2E*c,
                                 -K2E * (a*a + b*b + c*c));
        }
    }
    // own row coords, both batches (wave-uniform registers)
    float xa0[4], xa1[4], xa2[4], ya0[4], ya1[4], ya2[4];
    float xb0[4], xb1[4], xb2[4], yb0[4], yb1[4], yb2[4];
    #pragma unroll
    for (int k = 0; k < 4; ++k) {
        const float* p0 = x + 3 * (size_t)(base0 + rloc + k);
        xa0[k] = p0[0]; xa1[k] = p0[1]; xa2[k] = p0[2];
        const float* p1 = y + 3 * (size_t)(base0 + rloc + k);
        ya0[k] = p1[0]; ya1[k] = p1[1]; ya2[k] = p1[2];
        const float* p2 = x + 3 * (size_t)(base1 + rloc + k);
        xb0[k] = p2[0]; xb1[k] = p2[1]; xb2[k] = p2[2];
        const float* p3 = y + 3 * (size_t)(base1 + rloc + k);
        yb0[k] = p3[0]; yb1[k] = p3[1]; yb2[k] = p3[2];
    }
    __syncthreads();

    const int rr = ((lane & 1) << 1) | ((lane >> 1) & 1);

    // fused post+wait: one tid0 critical section between two block syncs
    #define PW(cpost, cwait, tgt) do { __syncthreads();                         \
        if (tid == 0) {                                                         \
            __threadfence(); atomicAdd((cpost), 1);                             \
            while (__hip_atomic_load((cwait), __ATOMIC_RELAXED,                 \
                                     __HIP_MEMORY_SCOPE_AGENT) < (tgt))         \
                __builtin_amdgcn_s_sleep(2);                                    \
            __threadfence();                                                    \
        }                                                                       \
        __syncthreads(); } while (0)

    #define PONLY(cpost) do { __syncthreads();                                  \
        if (tid == 0) { __threadfence(); atomicAdd((cpost), 1); }               \
        __syncthreads(); } while (0)

    #define WONLY(cwait, tgt) do { __syncthreads();                             \
        if (tid == 0) {                                                         \
            while (__hip_atomic_load((cwait), __ATOMIC_RELAXED,                 \
                                     __HIP_MEMORY_SCOPE_AGENT) < (tgt))         \
                __builtin_amdgcn_s_sleep(2);                                    \
            __threadfence();                                                    \
        }                                                                       \
        __syncthreads(); } while (0)

    // conflict-free contiguous b128 RMW of .w from dual array D
    #define STAGE_W(tab, D) do {                                                \
        _Pragma("unroll")                                                       \
        for (int v = 0; v < 2; ++v) {                                           \
            const int p = tid + (v << 10);                                      \
            float4 t = (tab)[p]; t.w = (D)[p]; (tab)[p] = t;                    \
        }                                                                       \
        __syncthreads(); } while (0)

    for (int it = 0; it < NITERS; ++it) {
        // ---- fA0 ----
        {
            float v = sumpass4(tY0, xa0, xa1, xa2, lane);
            if (lane < 4) Af[base0 + rloc + rr] = LMU - __log2f(v);
        }
        if (it > 0) { PW(c0, c1, 64 * it); STAGE_W(tY1, Bf + base1); }
        else        { PONLY(c0); }
        // ---- fA1 ----
        {
            float v = sumpass4(tY1, xb0, xb1, xb2, lane);
            if (lane < 4) Af[base1 + rloc + rr] = LMU - __log2f(v);
        }
        PW(c1, c0, 32 * (2 * it + 1));
        STAGE_W(tX0, Af + base0);
        // ---- gB0 ----
        {
            float v = sumpass4(tX0, ya0, ya1, ya2, lane);
            if (lane < 4) Bf[base0 + rloc + rr] = LMU - __log2f(v);
        }
        PW(c0, c1, 32 * (2 * it + 1));
        STAGE_W(tX1, Af + base1);
        // ---- gB1 ----
        {
            float v = sumpass4(tX1, yb0, yb1, yb2, lane);
            if (lane < 4) Bf[base1 + rloc + rr] = LMU - __log2f(v);
        }
        PW(c1, c0, 32 * (2 * it + 2));
        STAGE_W(tY0, Bf + base0);
    }
    // tail: final B1
    WONLY(c1, 64 * NITERS);
    STAGE_W(tY1, Bf + base1);

    // ---- epilogue ----
    {
        float s = epil4(tY0, tX0, xa0, xa1, xa2, rloc, lane)
                + epil4(tY1, tX1, xb0, xb1, xb2, rloc, lane);
        #pragma unroll
        for (int m = 32; m > 0; m >>= 1) s += __shfl_xor(s, m, 64);
        if (lane == 0) wsum[w] = s;
        __syncthreads();
        if (tid == 0) {
            float t = 0.f;
            #pragma unroll
            for (int i = 0; i < 16; ++i) t += wsum[i];
            atomicAdd(out, t * (1.0f / (float)BB));
        }
    }
    #undef PW
    #undef PONLY
    #undef WONLY
    #undef STAGE_W
}

extern "C" void kernel_launch(void* const* d_in, const int* in_sizes, int n_in,
                              void* d_out, int out_size, void* d_ws, size_t ws_size,
                              hipStream_t stream) {
    const float* x = (const float*)d_in[0];
    const float* y = (const float*)d_in[1];
    float* out = (float*)d_out;
    char* ws = (char*)d_ws;

    int*   cntb = (int*)ws;                                  // 16 x 256 B
    float* Af   = (float*)(ws + 4096);                       // 128 KB
    float* Bf   = (float*)(ws + 4096 + (size_t)BB*NN*sizeof(float));

    hipMemsetAsync(cntb, 0, 4096, stream);
    hipMemsetAsync(out, 0, sizeof(float), stream);

    const size_t shmem = (size_t)4 * NN * sizeof(float4);    // 128 KB
    hipFuncSetAttribute((const void*)emd_sinkhorn,
                        hipFuncAttributeMaxDynamicSharedMemorySize, (int)shmem);

    void* args[] = {(void*)&x, (void*)&y, (void*)&Af, (void*)&Bf,
                    (void*)&cntb, (void*)&out};
    hipError_t e = hipLaunchCooperativeKernel((const void*)emd_sinkhorn,
                                              dim3(256), dim3(1024),
                                              args, shmem, stream);
    if (e != hipSuccess) {
        hipLaunchKernelGGL(emd_sinkhorn, dim3(256), dim3(1024), shmem, stream,
                           x, y, Af, Bf, cntb, out);
    }
}

// Round 10
// 3279.215 us; speedup vs baseline: 1.2002x; 1.2002x over previous
//
#include <hip/hip_runtime.h>

#define BB 16
#define NN 2048
#define NITERS 100

// k = log2(e)/eps, eps = 0.05
#define K2E      28.853900817779268f
#define TWO_K2E  57.707801635558536f
#define INV2K    0.017328679513998632f   // 1/(2k)
#define INV_K2E  0.034657359027997264f
#define INV4K    0.008664339756999316f   // 1/(4k)
#define LMU      (-11.0f)                // log2(1/2048)

#if __has_builtin(__builtin_amdgcn_exp2f)
#define EXP2F(x) __builtin_amdgcn_exp2f(x)
#else
#define EXP2F(x) exp2f(x)
#endif

typedef float v2f __attribute__((ext_vector_type(2)));

// Sum-pass (R8-verified structure): 8 rows/wave (coords from LDS table u*,
// raw = u*INV2K), own j-half (1024 cols) of SoA tables t0..t2 + dual td.
// Packed-f32 d-computation (4 row-pairs). Wave-pair combine via pcomb.
// Returns combined row-sum on lanes 0..7 (row = rr involution).
__device__ __forceinline__ float sumpass(
    const float* __restrict__ u0, const float* __restrict__ u1,
    const float* __restrict__ u2,
    const float* __restrict__ t0, const float* __restrict__ t1,
    const float* __restrict__ t2, const float* __restrict__ td,
    int rloc, int jh, int lane, int w, float* pcomb)
{
    v2f xp0[4], xp1[4], xp2[4], acc2[4];
    #pragma unroll
    for (int p = 0; p < 4; ++p) {
        xp0[p] = (v2f){u0[rloc + 2*p] * INV2K, u0[rloc + 2*p + 1] * INV2K};
        xp1[p] = (v2f){u1[rloc + 2*p] * INV2K, u1[rloc + 2*p + 1] * INV2K};
        xp2[p] = (v2f){u2[rloc + 2*p] * INV2K, u2[rloc + 2*p + 1] * INV2K};
        acc2[p] = (v2f){0.f, 0.f};
    }
    const int jb = (jh << 10) + lane;
    #pragma unroll 2
    for (int s = 0; s < 16; ++s) {
        const int p = jb + (s << 6);
        const float a0 = t0[p], a1 = t1[p], a2 = t2[p], ad = td[p];
        const v2f a0v = (v2f){a0, a0}, a1v = (v2f){a1, a1};
        const v2f a2v = (v2f){a2, a2}, adv = (v2f){ad, ad};
        #pragma unroll
        for (int q = 0; q < 4; ++q) {
            v2f d = __builtin_elementwise_fma(xp0[q], a0v,
                    __builtin_elementwise_fma(xp1[q], a1v,
                    __builtin_elementwise_fma(xp2[q], a2v, adv)));
            acc2[q] += (v2f){EXP2F(d.x), EXP2F(d.y)};
        }
    }
    float acc[8];
    #pragma unroll
    for (int p = 0; p < 4; ++p) { acc[2*p] = acc2[p].x; acc[2*p+1] = acc2[p].y; }
    // multi-value butterfly (verified R3/R5/R8); lanes<8 end with row rr
    const bool b0 = lane & 1, b1 = lane & 2, b2 = lane & 4;
    float v4[4], v2_[2], v1;
    #pragma unroll
    for (int i = 0; i < 4; ++i) {
        float recv = __shfl_xor(b0 ? acc[i] : acc[i+4], 1, 64);
        v4[i] = (b0 ? acc[i+4] : acc[i]) + recv;
    }
    #pragma unroll
    for (int i = 0; i < 2; ++i) {
        float recv = __shfl_xor(b1 ? v4[i] : v4[i+2], 2, 64);
        v2_[i] = (b1 ? v4[i+2] : v4[i]) + recv;
    }
    {
        float recv = __shfl_xor(b2 ? v2_[0] : v2_[1], 4, 64);
        v1 = (b2 ? v2_[1] : v2_[0]) + recv;
    }
    v1 += __shfl_xor(v1, 8, 64);
    v1 += __shfl_xor(v1, 16, 64);
    v1 += __shfl_xor(v1, 32, 64);
    const int rr = ((lane & 1) << 2) | (lane & 2) | ((lane >> 2) & 1);
    if (lane < 8) pcomb[w * 8 + rr] = v1;
    __syncthreads();
    float S = 0.f;
    if (lane < 8) S = v1 + pcomb[(w ^ 1) * 8 + rr];
    return S;
}

// Epilogue partial (R8-verified): sum_j P_ij*C_ij, 8 rows x own j-half.
__device__ __forceinline__ float epil(
    const float* __restrict__ u0, const float* __restrict__ u1,
    const float* __restrict__ u2,
    const float* __restrict__ t0, const float* __restrict__ t1,
    const float* __restrict__ t2, const float* __restrict__ td,
    const float* __restrict__ sA, int rloc, int jh, int lane)
{
    float xr0[8], xr1[8], xr2[8], Ak[8], x2k[8];
    #pragma unroll
    for (int k = 0; k < 8; ++k) {
        xr0[k] = u0[rloc + k] * INV2K;
        xr1[k] = u1[rloc + k] * INV2K;
        xr2[k] = u2[rloc + k] * INV2K;
        Ak[k]  = sA[rloc + k];
        x2k[k] = K2E * (xr0[k]*xr0[k] + xr1[k]*xr1[k] + xr2[k]*xr2[k]);
    }
    float acc = 0.f;
    const int jb = (jh << 10) + lane;
    for (int s = 0; s < 16; ++s) {
        const int p = jb + (s << 6);
        const float a0 = t0[p], a1 = t1[p], a2 = t2[p], tb = td[p];
        const float q2 = (a0*a0 + a1*a1 + a2*a2) * INV4K;   // k|y|^2
        #pragma unroll
        for (int k = 0; k < 8; ++k) {
            float d = fmaf(xr0[k], a0, fmaf(xr1[k], a1, fmaf(xr2[k], a2, tb)));
            float P = EXP2F(d + Ak[k]);                       // exp(logP)
            float C = fmaxf((x2k[k] + q2 - (d - tb)) * INV_K2E, 0.f);
            acc = fmaf(P, C, acc);
        }
    }
    return acc;
}

// grid: 256 blocks x 1024 threads (1 block/CU). pair = blk&7 -> XCD-local:
// 32 blocks of batch pair (2p, 2p+1) on XCD p. Deterministic software
// pipeline (R8-verified): every wait has one full compute phase between the
// matching posts and the wait -> barrier pre-satisfied.
__global__ __launch_bounds__(1024) void emd_sinkhorn(
    const float* __restrict__ x, const float* __restrict__ y,
    float* __restrict__ Af, float* __restrict__ Bf,
    int* __restrict__ cntb, float* __restrict__ out)
{
    extern __shared__ float S[];     // 16*NN floats = 128 KB
    __shared__ float pcomb[16 * 8];
    __shared__ float wsum[16];

    const int tid  = threadIdx.x;
    const int lane = tid & 63;
    const int w    = tid >> 6;        // 0..15
    const int pr   = w >> 1;          // wave-pair 0..7
    const int jh   = w & 1;           // j-half
    const int blk  = blockIdx.x;
    const int pair = blk & 7;         // = XCD id under round-robin
    const int q    = blk >> 3;        // 0..31: row-slice within pair
    const int b0   = pair * 2, b1 = b0 + 1;
    const int base0 = b0 * NN, base1 = b1 * NN;
    const int rloc  = q * 64 + pr * 8;      // within-batch row base
    int* c0 = cntb + b0 * 64;
    int* c1 = cntb + b1 * 64;

    // LDS carve: per batch 8 slots of NN floats (SoA — conflict-free)
    float *sy00 = S,            *sy10 = S +  1*NN, *sy20 = S +  2*NN;
    float *sx00 = S +  3*NN,    *sx10 = S +  4*NN, *sx20 = S +  5*NN;
    float *sA0  = S +  6*NN,    *sB0  = S +  7*NN;
    float *sy01 = S +  8*NN,    *sy11 = S +  9*NN, *sy21 = S + 10*NN;
    float *sx01 = S + 11*NN,    *sx11 = S + 12*NN, *sx21 = S + 13*NN;
    float *sA1  = S + 14*NN,    *sB1  = S + 15*NN;

    // ---- prologue: stage 2k-scaled tables; B0 = -k|y|^2 ----
    #pragma unroll
    for (int v = 0; v < 2; ++v) {
        const int p = tid + (v << 10);
        {
            const float* px = x + 3 * (size_t)(base0 + p);
            sx00[p] = TWO_K2E * px[0]; sx10[p] = TWO_K2E * px[1]; sx20[p] = TWO_K2E * px[2];
            const float* py = y + 3 * (size_t)(base0 + p);
            const float a = py[0], b = py[1], c = py[2];
            sy00[p] = TWO_K2E * a; sy10[p] = TWO_K2E * b; sy20[p] = TWO_K2E * c;
            sB0[p]  = -K2E * (a*a + b*b + c*c);
        }
        {
            const float* px = x + 3 * (size_t)(base1 + p);
            sx01[p] = TWO_K2E * px[0]; sx11[p] = TWO_K2E * px[1]; sx21[p] = TWO_K2E * px[2];
            const float* py = y + 3 * (size_t)(base1 + p);
            const float a = py[0], b = py[1], c = py[2];
            sy01[p] = TWO_K2E * a; sy11[p] = TWO_K2E * b; sy21[p] = TWO_K2E * c;
            sB1[p]  = -K2E * (a*a + b*b + c*c);
        }
    }
    __syncthreads();

    const int rr = ((lane & 1) << 2) | (lane & 2) | ((lane >> 2) & 1);

    // fused post+wait: one tid0 critical section between two block syncs
    #define PW(cpost, cwait, tgt) do { __syncthreads();                         \
        if (tid == 0) {                                                         \
            __threadfence(); atomicAdd((cpost), 1);                             \
            while (__hip_atomic_load((cwait), __ATOMIC_RELAXED,                 \
                                     __HIP_MEMORY_SCOPE_AGENT) < (tgt))         \
                __builtin_amdgcn_s_sleep(1);                                    \
            __threadfence();                                                    \
        }                                                                       \
        __syncthreads(); } while (0)

    #define PONLY(cpost) do { __syncthreads();                                  \
        if (tid == 0) { __threadfence(); atomicAdd((cpost), 1); }               \
        __syncthreads(); } while (0)

    #define WONLY(cwait, tgt) do { __syncthreads();                             \
        if (tid == 0) {                                                         \
            while (__hip_atomic_load((cwait), __ATOMIC_RELAXED,                 \
                                     __HIP_MEMORY_SCOPE_AGENT) < (tgt))         \
                __builtin_amdgcn_s_sleep(1);                                    \
            __threadfence();                                                    \
        }                                                                       \
        __syncthreads(); } while (0)

    for (int it = 0; it < NITERS; ++it) {
        // ---- fA0 ----
        {
            float Sc = sumpass(sx00, sx10, sx20, sy00, sy10, sy20, sB0,
                               rloc, jh, lane, w, pcomb);
            if (lane < 8 && jh == 0) Af[base0 + rloc + rr] = LMU - __log2f(Sc);
        }
        // ---- post fA0; stage B1 of previous iteration ----
        if (it > 0) {
            PW(c0, c1, 64 * it);
            ((float2*)sB1)[tid] = ((const float2*)(Bf + base1))[tid];
            __syncthreads();
        } else {
            PONLY(c0);
        }
        // ---- fA1 ----
        {
            float Sc = sumpass(sx01, sx11, sx21, sy01, sy11, sy21, sB1,
                               rloc, jh, lane, w, pcomb);
            if (lane < 8 && jh == 0) Af[base1 + rloc + rr] = LMU - __log2f(Sc);
        }
        PW(c1, c0, 32 * (2 * it + 1));
        ((float2*)sA0)[tid] = ((const float2*)(Af + base0))[tid];
        __syncthreads();
        // ---- gB0 ----
        {
            float Sc = sumpass(sy00, sy10, sy20, sx00, sx10, sx20, sA0,
                               rloc, jh, lane, w, pcomb);
            if (lane < 8 && jh == 0) Bf[base0 + rloc + rr] = LMU - __log2f(Sc);
        }
        PW(c0, c1, 32 * (2 * it + 1));
        ((float2*)sA1)[tid] = ((const float2*)(Af + base1))[tid];
        __syncthreads();
        // ---- gB1 ----
        {
            float Sc = sumpass(sy01, sy11, sy21, sx01, sx11, sx21, sA1,
                               rloc, jh, lane, w, pcomb);
            if (lane < 8 && jh == 0) Bf[base1 + rloc + rr] = LMU - __log2f(Sc);
        }
        PW(c1, c0, 32 * (2 * it + 2));
        ((float2*)sB0)[tid] = ((const float2*)(Bf + base0))[tid];
        __syncthreads();
    }
    // final B1
    WONLY(c1, 64 * NITERS);
    ((float2*)sB1)[tid] = ((const float2*)(Bf + base1))[tid];
    __syncthreads();

    // ---- epilogue: own 64 rows of each batch, own j-half ----
    {
        float s = epil(sx00, sx10, sx20, sy00, sy10, sy20, sB0, sA0,
                       rloc, jh, lane)
                + epil(sx01, sx11, sx21, sy01, sy11, sy21, sB1, sA1,
                       rloc, jh, lane);
        #pragma unroll
        for (int m = 32; m > 0; m >>= 1) s += __shfl_xor(s, m, 64);
        if (lane == 0) wsum[w] = s;
        __syncthreads();
        if (tid == 0) {
            float t = 0.f;
            #pragma unroll
            for (int i = 0; i < 16; ++i) t += wsum[i];
            atomicAdd(out, t * (1.0f / (float)BB));
        }
    }
    #undef PW
    #undef PONLY
    #undef WONLY
}

extern "C" void kernel_launch(void* const* d_in, const int* in_sizes, int n_in,
                              void* d_out, int out_size, void* d_ws, size_t ws_size,
                              hipStream_t stream) {
    const float* x = (const float*)d_in[0];
    const float* y = (const float*)d_in[1];
    float* out = (float*)d_out;
    char* ws = (char*)d_ws;

    int*   cntb = (int*)ws;                                  // 16 x 256 B
    float* Af   = (float*)(ws + 4096);                       // 128 KB
    float* Bf   = (float*)(ws + 4096 + (size_t)BB*NN*sizeof(float));

    hipMemsetAsync(cntb, 0, 4096, stream);
    hipMemsetAsync(out, 0, sizeof(float), stream);

    const size_t shmem = (size_t)16 * NN * sizeof(float);    // 128 KB
    hipFuncSetAttribute((const void*)emd_sinkhorn,
                        hipFuncAttributeMaxDynamicSharedMemorySize, (int)shmem);

    void* args[] = {(void*)&x, (void*)&y, (void*)&Af, (void*)&Bf,
                    (void*)&cntb, (void*)&out};
    hipError_t e = hipLaunchCooperativeKernel((const void*)emd_sinkhorn,
                                              dim3(256), dim3(1024),
                                              args, shmem, stream);
    if (e != hipSuccess) {
        hipLaunchKernelGGL(emd_sinkhorn, dim3(256), dim3(1024), shmem, stream,
                           x, y, Af, Bf, cntb, out);
    }
}